// Round 1
// baseline (338.195 us; speedup 1.0000x reference)
//
#include <hip/hip_runtime.h>

#define X_B (32 * 207 * 64)     // 423936, b-stride in x/out
#define NCN (32 * 207)          // 6624 (c,n) tiles
#define NT 4                    // tiles per block
#define NBLK (NCN / NT)         // 1656 blocks
#define BN_EVAL 0.9999950000374997f

using s8v = __attribute__((ext_vector_type(8))) short;
using f4v = __attribute__((ext_vector_type(4))) float;

union UV { uint4 u; s8v s; };

// pack {bf16(lo), bf16(hi)} by truncation: 1 v_perm_b32
__device__ __forceinline__ unsigned pk(float lo, float hi) {
    union { float f; unsigned u; } a, b;
    a.f = lo; b.f = hi;
    return __builtin_amdgcn_perm(b.u, a.u, 0x07060302u);
}

// barrier that drains ONLY LDS ops — prefetched global loads stay in flight
// (__syncthreads would emit s_waitcnt vmcnt(0) and kill the pipeline)
__device__ __forceinline__ void lds_barrier() {
    asm volatile("s_waitcnt lgkmcnt(0)" ::: "memory");
    __builtin_amdgcn_s_barrier();
}

// One (c,n) tile. WCUR: rw fragments prefetched last tile (registers).
// WNXT: buffer to prefetch tile K+1 into. CUR/NXT: LDS A-buffer indices.
#define TILE(K, WCUR, WNXT, CUR, NXT, LAST)                                      \
    {                                                                            \
        const int cn = cn0 + (K);                                                \
        /* issue next-tile x load first (oldest in vmcnt FIFO) */                \
        float4 xnv;                                                              \
        if (!(LAST)) xnv = *(const float4*)(xstage_base + ((K) + 1) * 64);       \
        /* epilogue x re-reads: MUST issue before WNXT loads, else the */        \
        /* epilogue's vmcnt wait would drain the whole prefetch (in-order) */    \
        const float* xcol = x + (size_t)cn * 64 + o;                             \
        float xres0 = xcol[(size_t)(q * 4 + 0) * X_B];                           \
        float xres1 = xcol[(size_t)(q * 4 + 1) * X_B];                           \
        float xres2 = xcol[(size_t)(q * 4 + 2) * X_B];                           \
        float xres3 = xcol[(size_t)(q * 4 + 3) * X_B];                           \
        __builtin_amdgcn_sched_barrier(0); /* pin issue order xnv,xres < WNXT */ \
        if (!(LAST)) {                                                           \
            const float* wt = rw + (size_t)(cn + 1) * 8192 + o * 2 + 4 * q * 128;\
            _Pragma("unroll")                                                    \
            for (int u = 0; u < 16; ++u)                                         \
                WNXT[u] = *(const float2*)(wt + (size_t)((u >> 2) * 16 + (u & 3)) * 128); \
        }                                                                        \
        f4v accU = {0.f, 0.f, 0.f, 0.f};                                         \
        f4v accM = {0.f, 0.f, 0.f, 0.f};                                         \
        f4v accG = {0.f, 0.f, 0.f, 0.f};                                         \
        /* grouped matmul, K=128 (kappa=2i+d); B-frags from register prefetch */ \
        _Pragma("unroll")                                                        \
        for (int s = 0; s < 4; ++s) {                                            \
            UV bu;                                                               \
            bu.u.x = pk(WCUR[s * 4 + 0].x, WCUR[s * 4 + 0].y);                   \
            bu.u.y = pk(WCUR[s * 4 + 1].x, WCUR[s * 4 + 1].y);                   \
            bu.u.z = pk(WCUR[s * 4 + 2].x, WCUR[s * 4 + 2].y);                   \
            bu.u.w = pk(WCUR[s * 4 + 3].x, WCUR[s * 4 + 3].y);                   \
            UV au; au.u = *(const uint4*)&A1[CUR][nn * 136 + 32 * s + 8 * q];    \
            accU = __builtin_amdgcn_mfma_f32_16x16x32_bf16(au.s, bu.s, accU, 0, 0, 0); \
        }                                                                        \
        /* shared mlp+gate matmuls, K=64; B-frags are block-invariant regs */    \
        {                                                                        \
            UV a2u0; a2u0.u = *(const uint4*)&A2[CUR][nn * 72 + 8 * q];          \
            accM = __builtin_amdgcn_mfma_f32_16x16x32_bf16(a2u0.s, bmf0.s, accM, 0, 0, 0); \
            accG = __builtin_amdgcn_mfma_f32_16x16x32_bf16(a2u0.s, bgf0.s, accG, 0, 0, 0); \
            UV a2u1; a2u1.u = *(const uint4*)&A2[CUR][nn * 72 + 32 + 8 * q];     \
            accM = __builtin_amdgcn_mfma_f32_16x16x32_bf16(a2u1.s, bmf1.s, accM, 0, 0, 0); \
            accG = __builtin_amdgcn_mfma_f32_16x16x32_bf16(a2u1.s, bgf1.s, accG, 0, 0, 0); \
        }                                                                        \
        /* epilogue: D row = q*4+r, col = o */                                   \
        const float uconst = rb[cn] * (ow0 + ow1) + ob0;                         \
        float* ocol = out + (size_t)cn * 64 + o;                                 \
        {                                                                        \
            const float u0 = (accU[0] + uconst) * 0.125f;                        \
            const float u1 = (accU[1] + uconst) * 0.125f;                        \
            const float u2 = (accU[2] + uconst) * 0.125f;                        \
            const float u3 = (accU[3] + uconst) * 0.125f;                        \
            const float s0 = accM[0] + mbias, s1 = accM[1] + mbias;              \
            const float s2 = accM[2] + mbias, s3 = accM[3] + mbias;              \
            const float g0 = 1.f / (1.f + __expf(-(accG[0] + gbias)));           \
            const float g1 = 1.f / (1.f + __expf(-(accG[1] + gbias)));           \
            const float g2 = 1.f / (1.f + __expf(-(accG[2] + gbias)));           \
            const float g3 = 1.f / (1.f + __expf(-(accG[3] + gbias)));           \
            ocol[(size_t)(q * 4 + 0) * X_B] = g0 * u0 + (1.f - g0) * s0 + xres0; \
            ocol[(size_t)(q * 4 + 1) * X_B] = g1 * u1 + (1.f - g1) * s1 + xres1; \
            ocol[(size_t)(q * 4 + 2) * X_B] = g2 * u2 + (1.f - g2) * s2 + xres2; \
            ocol[(size_t)(q * 4 + 3) * X_B] = g3 * u3 + (1.f - g3) * s3 + xres3; \
        }                                                                        \
        /* stage tile K+1's x into the other A buffer; LDS-only barrier */       \
        if (!(LAST)) {                                                           \
            uint4 v;                                                             \
            v.x = pk(xnv.x * ow0, xnv.x * xnv.x * bnow1);                        \
            v.y = pk(xnv.y * ow0, xnv.y * xnv.y * bnow1);                        \
            v.z = pk(xnv.z * ow0, xnv.z * xnv.z * bnow1);                        \
            v.w = pk(xnv.w * ow0, xnv.w * xnv.w * bnow1);                        \
            *(uint4*)&A1[NXT][sb * 136 + si0 * 2] = v;                           \
            uint2 p; p.x = pk(xnv.x, xnv.y); p.y = pk(xnv.z, xnv.w);             \
            *(uint2*)&A2[NXT][sb * 72 + si0] = p;                                \
            lds_barrier();                                                       \
        }                                                                        \
    }

__global__ __launch_bounds__(256, 3)
void fused_ml_mfma(const float* __restrict__ x,
                   const float* __restrict__ rw,
                   const float* __restrict__ rb,
                   const float* __restrict__ mw,
                   const float* __restrict__ mb,
                   const float* __restrict__ gw,
                   const float* __restrict__ gb,
                   const float* __restrict__ ow,
                   const float* __restrict__ obp,
                   float* __restrict__ out)
{
    // A1[b][kappa=2i+d] = {x*ow0, x^2*BN*ow1}, row 128+8 pad, double-buffered
    __shared__ unsigned short A1[2][16 * 136];              // 2 x 4352 B
    // A2[b][i] = bf16(x), row 64+8 pad, double-buffered
    __shared__ unsigned short A2[2][16 * 72];               // 2 x 2304 B -> 13312 B total

    const int cn0 = blockIdx.x * NT;
    const int t = threadIdx.x;
    const float ow0 = ow[0], ow1 = ow[1];
    const float bnow1 = ow1 * BN_EVAL;

    const int l = t & 63, w = t >> 6, q = l >> 4, nn = l & 15;
    const int o = w * 16 + nn;            // this wave's o-tile column
    const int sb = t >> 4, si0 = (t & 15) * 4;   // x-staging coords

    const float* xstage_base = x + (size_t)sb * X_B + (size_t)cn0 * 64 + si0;

    // ---- prologue: issue everything, pack later ----
    // tile-0 x (for LDS staging)
    const float4 xv = *(const float4*)xstage_base;
    // mlp/gate weight fragments: per-lane MFMA B-frag = 8 consecutive i of
    // row o in native [o][i] layout -> load straight to regs, once per block
    const float* mrow = mw + o * 64 + 8 * q;
    const float* grow = gw + o * 64 + 8 * q;
    const float4 m00 = *(const float4*)(mrow);
    const float4 m01 = *(const float4*)(mrow + 4);
    const float4 m10 = *(const float4*)(mrow + 32);
    const float4 m11 = *(const float4*)(mrow + 36);
    const float4 g00 = *(const float4*)(grow);
    const float4 g01 = *(const float4*)(grow + 4);
    const float4 g10 = *(const float4*)(grow + 32);
    const float4 g11 = *(const float4*)(grow + 36);
    __builtin_amdgcn_sched_barrier(0);   // keep the above older than wb0 in vmcnt
    // tile-0 rw prefetch into registers
    float2 wb0[16], wb1[16];
    {
        const float* wt = rw + (size_t)cn0 * 8192 + o * 2 + 4 * q * 128;
#pragma unroll
        for (int u = 0; u < 16; ++u)
            wb0[u] = *(const float2*)(wt + (size_t)((u >> 2) * 16 + (u & 3)) * 128);
    }
    // pack block-invariant mlp/gate fragments
    UV bmf0, bmf1, bgf0, bgf1;
    bmf0.u.x = pk(m00.x, m00.y); bmf0.u.y = pk(m00.z, m00.w);
    bmf0.u.z = pk(m01.x, m01.y); bmf0.u.w = pk(m01.z, m01.w);
    bmf1.u.x = pk(m10.x, m10.y); bmf1.u.y = pk(m10.z, m10.w);
    bmf1.u.z = pk(m11.x, m11.y); bmf1.u.w = pk(m11.z, m11.w);
    bgf0.u.x = pk(g00.x, g00.y); bgf0.u.y = pk(g00.z, g00.w);
    bgf0.u.z = pk(g01.x, g01.y); bgf0.u.w = pk(g01.z, g01.w);
    bgf1.u.x = pk(g10.x, g10.y); bgf1.u.y = pk(g10.z, g10.w);
    bgf1.u.z = pk(g11.x, g11.y); bgf1.u.w = pk(g11.z, g11.w);
    const float mbias = mb[o], gbias = gb[o], ob0 = obp[0];

    // stage tile-0 x into A buffer 0
    {
        uint4 v;
        v.x = pk(xv.x * ow0, xv.x * xv.x * bnow1);
        v.y = pk(xv.y * ow0, xv.y * xv.y * bnow1);
        v.z = pk(xv.z * ow0, xv.z * xv.z * bnow1);
        v.w = pk(xv.w * ow0, xv.w * xv.w * bnow1);
        *(uint4*)&A1[0][sb * 136 + si0 * 2] = v;
        uint2 p; p.x = pk(xv.x, xv.y); p.y = pk(xv.z, xv.w);
        *(uint2*)&A2[0][sb * 72 + si0] = p;
    }
    lds_barrier();   // wb0 global loads stay in flight across this

    // ---- 4-tile software pipeline ----
    TILE(0, wb0, wb1, 0, 1, false)
    TILE(1, wb1, wb0, 1, 0, false)
    TILE(2, wb0, wb1, 0, 1, false)
    TILE(3, wb1, wb0, 1, 0, true)
}

extern "C" void kernel_launch(void* const* d_in, const int* in_sizes, int n_in,
                              void* d_out, int out_size, void* d_ws, size_t ws_size,
                              hipStream_t stream)
{
    const float* x   = (const float*)d_in[0];
    const float* rw  = (const float*)d_in[1];
    const float* rb  = (const float*)d_in[2];
    const float* mw  = (const float*)d_in[3];
    const float* mb  = (const float*)d_in[4];
    const float* gw  = (const float*)d_in[5];
    const float* gb  = (const float*)d_in[6];
    const float* ow  = (const float*)d_in[7];
    const float* ob  = (const float*)d_in[8];
    float* out = (float*)d_out;

    fused_ml_mfma<<<dim3(NBLK), dim3(256), 0, stream>>>(
        x, rw, rb, mw, mb, gw, gb, ow, ob, out);
}